// Round 11
// baseline (176.518 us; speedup 1.0000x reference)
//
#include <hip/hip_runtime.h>

#define DIN 128
#define HDIM 64
#define SLAB 32
#define OVF_CAP 65536
#define EPT 3  // edges per thread in k_front (3*256*1563 >= 1M)

__device__ __forceinline__ unsigned short f2bf(float f) {
    unsigned u = __float_as_uint(f);
    unsigned r = (u + 0x7fffu + ((u >> 16) & 1u)) >> 16;
    return (unsigned short)r;
}
__device__ __forceinline__ float lo16f(unsigned v) { return __uint_as_float(v << 16); }
__device__ __forceinline__ float hi16f(unsigned v) { return __uint_as_float(v & 0xffff0000u); }

// ---- fused front: every block does a 768-edge scatter slice AND a 64-node h1 tile.
// Atomics are issued after all staging loads (so no staging wait drains them) and
// consumed only after the GEMM -> atomic latency hides under compute.
__global__ __launch_bounds__(256) void k_front(
        const int* __restrict__ src, const int* __restrict__ dst,
        int* __restrict__ cursor, int* __restrict__ slab,
        int* __restrict__ ovf, int* __restrict__ govf, int E,
        const float* __restrict__ x, const float* __restrict__ W1,
        unsigned short* __restrict__ hs_bf, int n) {
    __shared__ float4 xs[64 * 16];
    __shared__ float4 ws[64 * 16];
    int t = threadIdx.x;
    int bid = blockIdx.x;
    int ty = t >> 4, tx = t & 15;
    int nodeBase = bid * 64;

    // edge slice loads (coalesced)
    int ebase = bid * (256 * EPT) + t;
    int d[EPT], s[EPT], p[EPT];
    bool ok[EPT];
    #pragma unroll
    for (int q = 0; q < EPT; ++q) {
        int e = ebase + q * 256;
        ok[q] = e < E;
        d[q] = ok[q] ? dst[e] : 0;
        s[q] = ok[q] ? src[e] : 0;
    }

    // GEMM staging loads, both K-chunks, into registers
    const float4* W14 = (const float4*)W1;
    const float4* x4 = (const float4*)(x + (size_t)nodeBase * DIN);
    int limf4 = (n - nodeBase) * (DIN / 4);
    float4 wg[2][4], xg[2][4];
    #pragma unroll
    for (int c = 0; c < 2; ++c)
        #pragma unroll
        for (int i = 0; i < 4; ++i) {
            int e = t + i * 256;
            int r = e >> 4, c4 = e & 15;
            int f4 = r * 32 + c * 16 + c4;
            wg[c][i] = W14[f4];
            xg[c][i] = (f4 < limf4) ? x4[f4] : make_float4(0.f, 0.f, 0.f, 0.f);
        }

    // atomics: issued last, consumed after the GEMM
    #pragma unroll
    for (int q = 0; q < EPT; ++q)
        if (ok[q]) p[q] = atomicAdd(&cursor[d[q]], 1);

    // h1 GEMM (unscaled): hs = x @ W1^T, reg-staged double-buffered LDS
    float acc[4][4] = {};
    #pragma unroll
    for (int c = 0; c < 2; ++c) {
        if (c) __syncthreads();
        #pragma unroll
        for (int i = 0; i < 4; ++i) {
            int e = t + i * 256;
            int r = e >> 4, c4 = e & 15;
            ws[r * 16 + (c4 ^ (r & 15))] = wg[c][i];
            xs[r * 16 + (c4 ^ (r & 15))] = xg[c][i];
        }
        __syncthreads();
        #pragma unroll 8
        for (int k4 = 0; k4 < 16; ++k4) {
            float4 xa[4], wb[4];
            #pragma unroll
            for (int i = 0; i < 4; ++i) {
                int r = ty + 16 * i;
                xa[i] = xs[r * 16 + (k4 ^ (r & 15))];
            }
            #pragma unroll
            for (int j = 0; j < 4; ++j) {
                int r = tx + 16 * j;
                wb[j] = ws[r * 16 + (k4 ^ (r & 15))];
            }
            #pragma unroll
            for (int i = 0; i < 4; ++i)
                #pragma unroll
                for (int j = 0; j < 4; ++j)
                    acc[i][j] += xa[i].x * wb[j].x + xa[i].y * wb[j].y +
                                 xa[i].z * wb[j].z + xa[i].w * wb[j].w;
        }
    }

    // slab stores (atomic results retired during GEMM)
    #pragma unroll
    for (int q = 0; q < EPT; ++q) {
        if (ok[q]) {
            if (p[q] < SLAB) {
                slab[(size_t)d[q] * SLAB + p[q]] = s[q];
            } else {
                int o = atomicAdd(govf, 1);
                if (o < OVF_CAP) { ovf[2 * o] = d[q]; ovf[2 * o + 1] = s[q]; }
            }
        }
    }

    // hs stores (unscaled)
    #pragma unroll
    for (int i = 0; i < 4; ++i) {
        int node = nodeBase + ty + 16 * i;
        if (node < n) {
            #pragma unroll
            for (int j = 0; j < 4; ++j)
                hs_bf[(size_t)node * HDIM + tx + 16 * j] = f2bf(acc[i][j]);
        }
    }
}

// ---- scale: hs_bf[n] *= rsqrt(deg[n]+1)  (8 threads/node, uint4 each) ----
__global__ __launch_bounds__(256) void k_scale(const int* __restrict__ cursor,
                                               unsigned short* __restrict__ hs_bf, int n) {
    int t = blockIdx.x * 256 + threadIdx.x;
    int node = t >> 3;
    if (node >= n) return;
    float dn = rsqrtf((float)cursor[node] + 1.0f);
    unsigned* p = (unsigned*)(hs_bf + ((size_t)node << 6) + 8 * (t & 7));
    uint4 v = *(uint4*)p;
    uint4 o;
    o.x = (unsigned)f2bf(lo16f(v.x) * dn) | ((unsigned)f2bf(hi16f(v.x) * dn) << 16);
    o.y = (unsigned)f2bf(lo16f(v.y) * dn) | ((unsigned)f2bf(hi16f(v.y) * dn) << 16);
    o.z = (unsigned)f2bf(lo16f(v.z) * dn) | ((unsigned)f2bf(hi16f(v.z) * dn) << 16);
    o.w = (unsigned)f2bf(lo16f(v.w) * dn) | ((unsigned)f2bf(hi16f(v.w) * dn) << 16);
    *(uint4*)p = o;
}

// ---- fused back: gather 64 nodes -> activated h tile in LDS -> dual-head GEMM ----
__global__ __launch_bounds__(256) void k_gatherout(
        const int* __restrict__ cursor, const int* __restrict__ slab,
        const unsigned short* __restrict__ hs_bf,
        const int* __restrict__ govf, const int* __restrict__ ovf,
        const float* __restrict__ b1,
        const float* __restrict__ Wmu, const float* __restrict__ bmu,
        const float* __restrict__ Wlv, const float* __restrict__ blv,
        float* __restrict__ out, int n) {
    __shared__ float4 xs[64 * 16];   // activated h tile (16 KB)
    __shared__ uint2 wsb[128 * 16];  // packed-bf16 [Wmu;Wlv] (16 KB)
    int t = threadIdx.x;
    int nodeBase = blockIdx.x * 64;

    // stage packed weights
    #pragma unroll
    for (int i = 0; i < 8; ++i) {
        int e = t + i * 256;  // 0..2047
        int r = e >> 4, c4 = e & 15;
        const float4* Wr = (r < 64) ? ((const float4*)Wmu + r * 16)
                                    : ((const float4*)Wlv + (r - 64) * 16);
        float4 wv = Wr[c4];
        uint2 pk;
        pk.x = (unsigned)f2bf(wv.x) | ((unsigned)f2bf(wv.y) << 16);
        pk.y = (unsigned)f2bf(wv.z) | ((unsigned)f2bf(wv.w) << 16);
        wsb[r * 16 + (c4 ^ (r & 15))] = pk;
    }

    // gather phase: 4 waves x 16 nodes; 8 edge-groups x 8 feat-lanes (uint4)
    int lane = t & 63, wave = t >> 6;
    int grp = lane >> 3, w8 = lane & 7;
    float4 bb0 = ((const float4*)b1)[2 * w8];
    float4 bb1 = ((const float4*)b1)[2 * w8 + 1];
    int novf = govf[0];
    if (novf > OVF_CAP) novf = OVF_CAP;
    for (int nn = 0; nn < 16; ++nn) {
        int node = nodeBase + wave * 16 + nn;
        if (node >= n) break;
        int c = cursor[node];
        int cs = (c < SLAB) ? c : SLAB;
        int sv = (lane < cs) ? slab[(size_t)node * SLAB + lane] : 0;
        uint4 v0 = *(const uint4*)(hs_bf + ((size_t)node << 6) + 8 * w8);
        float sw = (grp == 0) ? 1.f : 0.f;
        float a0 = sw * lo16f(v0.x), a1 = sw * hi16f(v0.x);
        float a2 = sw * lo16f(v0.y), a3 = sw * hi16f(v0.y);
        float a4 = sw * lo16f(v0.z), a5 = sw * hi16f(v0.z);
        float a6 = sw * lo16f(v0.w), a7 = sw * hi16f(v0.w);
        int nfull = cs >> 3;
        for (int q = 0; q < nfull; ++q) {
            int s = __shfl(sv, 8 * q + grp);
            uint4 v = *(const uint4*)(hs_bf + ((size_t)s << 6) + 8 * w8);
            a0 += lo16f(v.x); a1 += hi16f(v.x);
            a2 += lo16f(v.y); a3 += hi16f(v.y);
            a4 += lo16f(v.z); a5 += hi16f(v.z);
            a6 += lo16f(v.w); a7 += hi16f(v.w);
        }
        int r = cs & 7;
        if (r) {
            int e = 8 * nfull + grp;
            float wt = (grp < r) ? 1.f : 0.f;
            int s = __shfl(sv, (e < SLAB) ? e : 0);
            uint4 v = *(const uint4*)(hs_bf + ((size_t)s << 6) + 8 * w8);
            a0 += wt * lo16f(v.x); a1 += wt * hi16f(v.x);
            a2 += wt * lo16f(v.y); a3 += wt * hi16f(v.y);
            a4 += wt * lo16f(v.z); a5 += wt * hi16f(v.z);
            a6 += wt * lo16f(v.w); a7 += wt * hi16f(v.w);
        }
        #define RED(A) A += __shfl_xor(A, 8); A += __shfl_xor(A, 16); A += __shfl_xor(A, 32);
        RED(a0) RED(a1) RED(a2) RED(a3) RED(a4) RED(a5) RED(a6) RED(a7)
        #undef RED
        if (lane < 8) {
            // rare overflow edges for this node (deg > SLAB): scan side list
            if (c > SLAB) {
                for (int i = 0; i < novf; ++i) {
                    if (ovf[2 * i] == node) {
                        int s = ovf[2 * i + 1];
                        uint4 v = *(const uint4*)(hs_bf + ((size_t)s << 6) + 8 * lane);
                        a0 += lo16f(v.x); a1 += hi16f(v.x);
                        a2 += lo16f(v.y); a3 += hi16f(v.y);
                        a4 += lo16f(v.z); a5 += hi16f(v.z);
                        a6 += lo16f(v.w); a7 += hi16f(v.w);
                    }
                }
            }
            float dn = rsqrtf((float)c + 1.0f);
            int rr = wave * 16 + nn;
            float4 h0, h1;
            h0.x = fmaxf(fmaf(a0, dn, bb0.x), 0.f);
            h0.y = fmaxf(fmaf(a1, dn, bb0.y), 0.f);
            h0.z = fmaxf(fmaf(a2, dn, bb0.z), 0.f);
            h0.w = fmaxf(fmaf(a3, dn, bb0.w), 0.f);
            h1.x = fmaxf(fmaf(a4, dn, bb1.x), 0.f);
            h1.y = fmaxf(fmaf(a5, dn, bb1.y), 0.f);
            h1.z = fmaxf(fmaf(a6, dn, bb1.z), 0.f);
            h1.w = fmaxf(fmaf(a7, dn, bb1.w), 0.f);
            xs[rr * 16 + ((2 * w8) ^ (rr & 15))] = h0;
            xs[rr * 16 + ((2 * w8 + 1) ^ (rr & 15))] = h1;
        }
    }
    __syncthreads();

    // out GEMM: 64 nodes x 128 outs, packed-bf16 weights
    int ty = t >> 4, tx = t & 15;
    float bias[8];
    #pragma unroll
    for (int j = 0; j < 8; ++j) {
        int o = tx + 16 * j;
        bias[j] = (o < 64) ? bmu[o] : blv[o - 64];
    }
    float acc[4][8] = {};
    #pragma unroll 4
    for (int k4 = 0; k4 < 16; ++k4) {
        float4 xa[4];
        #pragma unroll
        for (int i = 0; i < 4; ++i) {
            int r = ty + 16 * i;
            xa[i] = xs[r * 16 + (k4 ^ (r & 15))];
        }
        #pragma unroll
        for (int j = 0; j < 8; ++j) {
            int r = tx + 16 * j;
            uint2 wv = wsb[r * 16 + (k4 ^ (r & 15))];
            float w0 = lo16f(wv.x), w1 = hi16f(wv.x);
            float w2 = lo16f(wv.y), w3 = hi16f(wv.y);
            #pragma unroll
            for (int i = 0; i < 4; ++i)
                acc[i][j] += xa[i].x * w0 + xa[i].y * w1 + xa[i].z * w2 + xa[i].w * w3;
        }
    }
    #pragma unroll
    for (int i = 0; i < 4; ++i) {
        int node = nodeBase + ty + 16 * i;
        if (node < n) {
            #pragma unroll
            for (int j = 0; j < 8; ++j) {
                int o = tx + 16 * j;
                float val = acc[i][j] + bias[j];
                if (o < 64)
                    out[(size_t)node * HDIM + o] = val;
                else
                    out[(size_t)n * HDIM + (size_t)node * HDIM + (o - 64)] = val;
            }
        }
    }
}

extern "C" void kernel_launch(void* const* d_in, const int* in_sizes, int n_in,
                              void* d_out, int out_size, void* d_ws, size_t ws_size,
                              hipStream_t stream) {
    const float* x   = (const float*)d_in[0];
    const int*   ei  = (const int*)d_in[1];
    const float* W1  = (const float*)d_in[2];
    const float* b1  = (const float*)d_in[3];
    const float* Wmu = (const float*)d_in[4];
    const float* bmu = (const float*)d_in[5];
    const float* Wlv = (const float*)d_in[6];
    const float* blv = (const float*)d_in[7];
    float* out = (float*)d_out;

    const int N = in_sizes[0] / DIN;   // 100000
    const int E = in_sizes[1] / 2;     // 1000000
    const int* src = ei;
    const int* dst = ei + E;

    auto align256 = [](size_t b) { return (b + 255) & ~(size_t)255; };
    char* ws = (char*)d_ws;
    size_t off = 0;
    int* cursor = (int*)(ws + off); off += align256((size_t)N * 4);
    int* govf   = (int*)(ws + off); off += 256;
    int* slab   = (int*)(ws + off); off += align256((size_t)N * SLAB * 4);
    int* ovf    = (int*)(ws + off); off += align256((size_t)OVF_CAP * 2 * 4);
    unsigned short* hs_bf = (unsigned short*)(ws + off);
    off += align256((size_t)N * HDIM * 2);

    hipMemsetAsync(cursor, 0, align256((size_t)N * 4) + 256, stream);

    int blocks = (N + 63) / 64;  // 1563; also covers E: 3*256*1563 >= 1M
    k_front<<<blocks, 256, 0, stream>>>(src, dst, cursor, slab, ovf, govf, E,
                                        x, W1, hs_bf, N);
    k_scale<<<(N * 8 + 255) / 256, 256, 0, stream>>>(cursor, hs_bf, N);
    k_gatherout<<<blocks, 256, 0, stream>>>(cursor, slab, hs_bf, govf, ovf,
                                            b1, Wmu, bmu, Wlv, blv, out, N);
}

// Round 12
// 161.840 us; speedup vs baseline: 1.0907x; 1.0907x over previous
//
#include <hip/hip_runtime.h>

#define DIN 128
#define HDIM 64
#define SLAB 32
#define OVF_CAP 65536
#define EPT 3  // edges per thread in k_front (3*256*1563 >= 1M)

__device__ __forceinline__ unsigned short f2bf(float f) {
    unsigned u = __float_as_uint(f);
    unsigned r = (u + 0x7fffu + ((u >> 16) & 1u)) >> 16;
    return (unsigned short)r;
}
__device__ __forceinline__ float lo16f(unsigned v) { return __uint_as_float(v << 16); }
__device__ __forceinline__ float hi16f(unsigned v) { return __uint_as_float(v & 0xffff0000u); }

// ---- fused front: every block does a 768-edge scatter slice AND a 64-node h1 tile.
__global__ __launch_bounds__(256) void k_front(
        const int* __restrict__ src, const int* __restrict__ dst,
        int* __restrict__ cursor, int* __restrict__ slab,
        int* __restrict__ ovf, int* __restrict__ govf, int E,
        const float* __restrict__ x, const float* __restrict__ W1,
        unsigned short* __restrict__ hs_bf, int n) {
    __shared__ float4 xs[64 * 16];
    __shared__ float4 ws[64 * 16];
    int t = threadIdx.x;
    int bid = blockIdx.x;
    int ty = t >> 4, tx = t & 15;
    int nodeBase = bid * 64;

    // edge slice loads (coalesced)
    int ebase = bid * (256 * EPT) + t;
    int d[EPT], s[EPT], p[EPT];
    bool ok[EPT];
    #pragma unroll
    for (int q = 0; q < EPT; ++q) {
        int e = ebase + q * 256;
        ok[q] = e < E;
        d[q] = ok[q] ? dst[e] : 0;
        s[q] = ok[q] ? src[e] : 0;
    }

    // GEMM staging loads, both K-chunks, into registers
    const float4* W14 = (const float4*)W1;
    const float4* x4 = (const float4*)(x + (size_t)nodeBase * DIN);
    int limf4 = (n - nodeBase) * (DIN / 4);
    float4 wg[2][4], xg[2][4];
    #pragma unroll
    for (int c = 0; c < 2; ++c)
        #pragma unroll
        for (int i = 0; i < 4; ++i) {
            int e = t + i * 256;
            int r = e >> 4, c4 = e & 15;
            int f4 = r * 32 + c * 16 + c4;
            wg[c][i] = W14[f4];
            xg[c][i] = (f4 < limf4) ? x4[f4] : make_float4(0.f, 0.f, 0.f, 0.f);
        }

    // atomics: issued after staging loads, consumed after the GEMM
    #pragma unroll
    for (int q = 0; q < EPT; ++q)
        if (ok[q]) p[q] = atomicAdd(&cursor[d[q]], 1);

    // h1 GEMM (unscaled)
    float acc[4][4] = {};
    #pragma unroll
    for (int c = 0; c < 2; ++c) {
        if (c) __syncthreads();
        #pragma unroll
        for (int i = 0; i < 4; ++i) {
            int e = t + i * 256;
            int r = e >> 4, c4 = e & 15;
            ws[r * 16 + (c4 ^ (r & 15))] = wg[c][i];
            xs[r * 16 + (c4 ^ (r & 15))] = xg[c][i];
        }
        __syncthreads();
        #pragma unroll 8
        for (int k4 = 0; k4 < 16; ++k4) {
            float4 xa[4], wb[4];
            #pragma unroll
            for (int i = 0; i < 4; ++i) {
                int r = ty + 16 * i;
                xa[i] = xs[r * 16 + (k4 ^ (r & 15))];
            }
            #pragma unroll
            for (int j = 0; j < 4; ++j) {
                int r = tx + 16 * j;
                wb[j] = ws[r * 16 + (k4 ^ (r & 15))];
            }
            #pragma unroll
            for (int i = 0; i < 4; ++i)
                #pragma unroll
                for (int j = 0; j < 4; ++j)
                    acc[i][j] += xa[i].x * wb[j].x + xa[i].y * wb[j].y +
                                 xa[i].z * wb[j].z + xa[i].w * wb[j].w;
        }
    }

    // slab stores (atomic results retired during GEMM)
    #pragma unroll
    for (int q = 0; q < EPT; ++q) {
        if (ok[q]) {
            if (p[q] < SLAB) {
                slab[(size_t)d[q] * SLAB + p[q]] = s[q];
            } else {
                int o = atomicAdd(govf, 1);
                if (o < OVF_CAP) { ovf[2 * o] = d[q]; ovf[2 * o + 1] = s[q]; }
            }
        }
    }

    // hs stores (unscaled)
    #pragma unroll
    for (int i = 0; i < 4; ++i) {
        int node = nodeBase + ty + 16 * i;
        if (node < n) {
            #pragma unroll
            for (int j = 0; j < 4; ++j)
                hs_bf[(size_t)node * HDIM + tx + 16 * j] = f2bf(acc[i][j]);
        }
    }
}

// ---- scale: hs_bf[n] *= rsqrt(deg[n]+1)  (8 threads/node, uint4 each) ----
__global__ __launch_bounds__(256) void k_scale(const int* __restrict__ cursor,
                                               unsigned short* __restrict__ hs_bf, int n) {
    int t = blockIdx.x * 256 + threadIdx.x;
    int node = t >> 3;
    if (node >= n) return;
    float dn = rsqrtf((float)cursor[node] + 1.0f);
    unsigned* p = (unsigned*)(hs_bf + ((size_t)node << 6) + 8 * (t & 7));
    uint4 v = *(uint4*)p;
    uint4 o;
    o.x = (unsigned)f2bf(lo16f(v.x) * dn) | ((unsigned)f2bf(hi16f(v.x) * dn) << 16);
    o.y = (unsigned)f2bf(lo16f(v.y) * dn) | ((unsigned)f2bf(hi16f(v.y) * dn) << 16);
    o.z = (unsigned)f2bf(lo16f(v.z) * dn) | ((unsigned)f2bf(hi16f(v.z) * dn) << 16);
    o.w = (unsigned)f2bf(lo16f(v.w) * dn) | ((unsigned)f2bf(hi16f(v.w) * dn) << 16);
    *(uint4*)p = o;
}

// ---- gather: h[node] = hs[node] + sum_slab hs[src]  (raw, pre-activation) ----
// 8 edge-groups x 8 feat-lanes (uint4 = 8 bf16 = 16B each).
__global__ __launch_bounds__(256) void k_gather(const int* __restrict__ cursor,
                                                const int* __restrict__ slab,
                                                const unsigned short* __restrict__ hs_bf,
                                                float* __restrict__ h, int n) {
    int tid = threadIdx.x;
    int lane = tid & 63, wave = tid >> 6;
    int grp = lane >> 3;   // edge slot within octet
    int w8 = lane & 7;     // feature octet: feats 8*w8..8*w8+7
    const int NPW = 8;
    int base = blockIdx.x * (4 * NPW) + wave * NPW;
    for (int nn = 0; nn < NPW; ++nn) {
        int node = base + nn;
        if (node >= n) break;
        int c = cursor[node];
        int cs = (c < SLAB) ? c : SLAB;
        int sv = (lane < cs) ? slab[(size_t)node * SLAB + lane] : 0;
        uint4 v0 = *(const uint4*)(hs_bf + ((size_t)node << 6) + 8 * w8);
        float sw = (grp == 0) ? 1.f : 0.f;
        float a0 = sw * lo16f(v0.x), a1 = sw * hi16f(v0.x);
        float a2 = sw * lo16f(v0.y), a3 = sw * hi16f(v0.y);
        float a4 = sw * lo16f(v0.z), a5 = sw * hi16f(v0.z);
        float a6 = sw * lo16f(v0.w), a7 = sw * hi16f(v0.w);
        int nfull = cs >> 3;
        for (int q = 0; q < nfull; ++q) {
            int s = __shfl(sv, 8 * q + grp);
            uint4 v = *(const uint4*)(hs_bf + ((size_t)s << 6) + 8 * w8);
            a0 += lo16f(v.x); a1 += hi16f(v.x);
            a2 += lo16f(v.y); a3 += hi16f(v.y);
            a4 += lo16f(v.z); a5 += hi16f(v.z);
            a6 += lo16f(v.w); a7 += hi16f(v.w);
        }
        int r = cs & 7;
        if (r) {
            int e = 8 * nfull + grp;
            float wt = (grp < r) ? 1.f : 0.f;
            int s = __shfl(sv, (e < SLAB) ? e : 0);
            uint4 v = *(const uint4*)(hs_bf + ((size_t)s << 6) + 8 * w8);
            a0 += wt * lo16f(v.x); a1 += wt * hi16f(v.x);
            a2 += wt * lo16f(v.y); a3 += wt * hi16f(v.y);
            a4 += wt * lo16f(v.z); a5 += wt * hi16f(v.z);
            a6 += wt * lo16f(v.w); a7 += wt * hi16f(v.w);
        }
        #define RED(A) A += __shfl_xor(A, 8); A += __shfl_xor(A, 16); A += __shfl_xor(A, 32);
        RED(a0) RED(a1) RED(a2) RED(a3) RED(a4) RED(a5) RED(a6) RED(a7)
        #undef RED
        if (lane < 8) {
            float* hp = h + ((size_t)node << 6) + 8 * w8;
            *(float4*)hp = make_float4(a0, a1, a2, a3);
            *(float4*)(hp + 4) = make_float4(a4, a5, a6, a7);
        }
    }
}

// ---- rare overflow edges (deg > SLAB): atomic add into raw h ----
__global__ __launch_bounds__(256) void k_overflow(const int* __restrict__ govf,
                                                  const int* __restrict__ ovf,
                                                  const unsigned short* __restrict__ hs_bf,
                                                  float* __restrict__ h) {
    int novf = govf[0];
    if (novf > OVF_CAP) novf = OVF_CAP;
    int wid = (blockIdx.x * 256 + threadIdx.x) >> 6;
    int lane = threadIdx.x & 63;
    int nw = (gridDim.x * 256) >> 6;
    for (int i = wid; i < novf; i += nw) {
        int d = ovf[2 * i], s = ovf[2 * i + 1];
        atomicAdd(&h[(size_t)d * HDIM + lane],
                  lo16f((unsigned)hs_bf[(size_t)s * HDIM + lane]));
    }
}

// ---- out GEMM, packed-bf16 weights, activation fused on h load ----
__global__ __launch_bounds__(256) void k_out(const float* __restrict__ h,
                                             const int* __restrict__ cursor,
                                             const float* __restrict__ b1,
                                             const float* __restrict__ Wmu,
                                             const float* __restrict__ bmu,
                                             const float* __restrict__ Wlv,
                                             const float* __restrict__ blv,
                                             float* __restrict__ out, int n) {
    __shared__ float4 xs[64 * 16];   // activated h tile (16 KB)
    __shared__ uint2 wsb[128 * 16];  // packed-bf16 [Wmu;Wlv] (16 KB)
    int t = threadIdx.x;
    int ty = t >> 4;
    int tx = t & 15;
    int nodeBase = blockIdx.x * 64;

    // stage packed weights
    #pragma unroll
    for (int i = 0; i < 8; ++i) {
        int e = t + i * 256;  // 0..2047
        int r = e >> 4, c4 = e & 15;
        const float4* Wr = (r < 64) ? ((const float4*)Wmu + r * 16)
                                    : ((const float4*)Wlv + (r - 64) * 16);
        float4 wv = Wr[c4];
        uint2 pk;
        pk.x = (unsigned)f2bf(wv.x) | ((unsigned)f2bf(wv.y) << 16);
        pk.y = (unsigned)f2bf(wv.z) | ((unsigned)f2bf(wv.w) << 16);
        wsb[r * 16 + (c4 ^ (r & 15))] = pk;
    }
    // stage h tile with fused activation
    const float4* h4 = (const float4*)(h + (size_t)nodeBase * HDIM);
    int limf4 = (n - nodeBase) * (HDIM / 4);
    #pragma unroll
    for (int i = 0; i < 4; ++i) {
        int f = t + i * 256;
        int r = f >> 4, c4 = f & 15;
        float4 v = make_float4(0.f, 0.f, 0.f, 0.f);
        if (f < limf4) {
            v = h4[f];
            float dn = rsqrtf((float)cursor[nodeBase + r] + 1.0f);
            float4 bb = ((const float4*)b1)[c4];
            v.x = fmaxf(fmaf(v.x, dn, bb.x), 0.f);
            v.y = fmaxf(fmaf(v.y, dn, bb.y), 0.f);
            v.z = fmaxf(fmaf(v.z, dn, bb.z), 0.f);
            v.w = fmaxf(fmaf(v.w, dn, bb.w), 0.f);
        }
        xs[r * 16 + (c4 ^ (r & 15))] = v;
    }
    float bias[8];
    #pragma unroll
    for (int j = 0; j < 8; ++j) {
        int o = tx + 16 * j;
        bias[j] = (o < 64) ? bmu[o] : blv[o - 64];
    }
    __syncthreads();

    float acc[4][8] = {};
    #pragma unroll 4
    for (int k4 = 0; k4 < 16; ++k4) {
        float4 xa[4];
        #pragma unroll
        for (int i = 0; i < 4; ++i) {
            int r = ty + 16 * i;
            xa[i] = xs[r * 16 + (k4 ^ (r & 15))];
        }
        #pragma unroll
        for (int j = 0; j < 8; ++j) {
            int r = tx + 16 * j;
            uint2 wv = wsb[r * 16 + (k4 ^ (r & 15))];
            float w0 = lo16f(wv.x), w1 = hi16f(wv.x);
            float w2 = lo16f(wv.y), w3 = hi16f(wv.y);
            #pragma unroll
            for (int i = 0; i < 4; ++i)
                acc[i][j] += xa[i].x * w0 + xa[i].y * w1 + xa[i].z * w2 + xa[i].w * w3;
        }
    }
    #pragma unroll
    for (int i = 0; i < 4; ++i) {
        int node = nodeBase + ty + 16 * i;
        if (node < n) {
            #pragma unroll
            for (int j = 0; j < 8; ++j) {
                int o = tx + 16 * j;
                float val = acc[i][j] + bias[j];
                if (o < 64)
                    out[(size_t)node * HDIM + o] = val;
                else
                    out[(size_t)n * HDIM + (size_t)node * HDIM + (o - 64)] = val;
            }
        }
    }
}

extern "C" void kernel_launch(void* const* d_in, const int* in_sizes, int n_in,
                              void* d_out, int out_size, void* d_ws, size_t ws_size,
                              hipStream_t stream) {
    const float* x   = (const float*)d_in[0];
    const int*   ei  = (const int*)d_in[1];
    const float* W1  = (const float*)d_in[2];
    const float* b1  = (const float*)d_in[3];
    const float* Wmu = (const float*)d_in[4];
    const float* bmu = (const float*)d_in[5];
    const float* Wlv = (const float*)d_in[6];
    const float* blv = (const float*)d_in[7];
    float* out = (float*)d_out;

    const int N = in_sizes[0] / DIN;   // 100000
    const int E = in_sizes[1] / 2;     // 1000000
    const int* src = ei;
    const int* dst = ei + E;

    auto align256 = [](size_t b) { return (b + 255) & ~(size_t)255; };
    char* ws = (char*)d_ws;
    size_t off = 0;
    int* cursor = (int*)(ws + off); off += align256((size_t)N * 4);
    int* govf   = (int*)(ws + off); off += 256;
    int* slab   = (int*)(ws + off); off += align256((size_t)N * SLAB * 4);
    int* ovf    = (int*)(ws + off); off += align256((size_t)OVF_CAP * 2 * 4);
    unsigned short* hs_bf = (unsigned short*)(ws + off);
    off += align256((size_t)N * HDIM * 2);
    float* h = (float*)(ws + off); off += align256((size_t)N * HDIM * 4);

    hipMemsetAsync(cursor, 0, align256((size_t)N * 4) + 256, stream);

    int blocks = (N + 63) / 64;  // 1563; also covers E: 3*256*1563 >= 1M
    k_front<<<blocks, 256, 0, stream>>>(src, dst, cursor, slab, ovf, govf, E,
                                        x, W1, hs_bf, N);
    k_scale<<<(N * 8 + 255) / 256, 256, 0, stream>>>(cursor, hs_bf, N);
    k_gather<<<(N + 31) / 32, 256, 0, stream>>>(cursor, slab, hs_bf, h, N);
    k_overflow<<<8, 256, 0, stream>>>(govf, ovf, hs_bf, h);
    k_out<<<(N + 63) / 64, 256, 0, stream>>>(h, cursor, b1, Wmu, bmu, Wlv, blv, out, N);
}

// Round 13
// 147.453 us; speedup vs baseline: 1.1971x; 1.0976x over previous
//
#include <hip/hip_runtime.h>

#define DIN 128
#define HDIM 64
#define SLAB 32
#define OVF_CAP 65536

__device__ __forceinline__ unsigned short f2bf(float f) {
    unsigned u = __float_as_uint(f);
    unsigned r = (u + 0x7fffu + ((u >> 16) & 1u)) >> 16;
    return (unsigned short)r;
}
__device__ __forceinline__ float lo16f(unsigned v) { return __uint_as_float(v << 16); }
__device__ __forceinline__ float hi16f(unsigned v) { return __uint_as_float(v & 0xffff0000u); }

// ---- fused front, parity-interleaved roles: 5 of every 13 blocks scatter
//      (1024 edges each), 8 of every 13 do a 64-node h1 GEMM tile (raw bf16).
__global__ __launch_bounds__(256) void k_front(
        const int* __restrict__ src, const int* __restrict__ dst,
        int* __restrict__ cursor, int* __restrict__ slab,
        int* __restrict__ ovf, int* __restrict__ govf, int E, int scBlocks,
        const float* __restrict__ x, const float* __restrict__ W1,
        unsigned short* __restrict__ hs_bf, int n, int gBlocks) {
    __shared__ float4 xs[64 * 16];
    __shared__ float4 ws[64 * 16];
    int t = threadIdx.x;
    int cyc = blockIdx.x / 13, r = blockIdx.x % 13;

    if (r < 5) {
        // ---------- scatter role ----------
        int sid = cyc * 5 + r;
        if (sid >= scBlocks) return;
        int ebase = sid * 1024 + t;
        int d[4], s[4], p[4];
        bool ok[4];
        #pragma unroll
        for (int q = 0; q < 4; ++q) {
            int e = ebase + q * 256;
            ok[q] = e < E;
            d[q] = ok[q] ? dst[e] : 0;
            s[q] = ok[q] ? src[e] : 0;
        }
        #pragma unroll
        for (int q = 0; q < 4; ++q)
            if (ok[q]) p[q] = atomicAdd(&cursor[d[q]], 1);
        #pragma unroll
        for (int q = 0; q < 4; ++q) {
            if (ok[q]) {
                if (p[q] < SLAB) {
                    slab[(size_t)d[q] * SLAB + p[q]] = s[q];
                } else {
                    int o = atomicAdd(govf, 1);
                    if (o < OVF_CAP) { ovf[2 * o] = d[q]; ovf[2 * o + 1] = s[q]; }
                }
            }
        }
        return;
    }

    // ---------- h1 GEMM role (unscaled): hs_bf = bf16(x @ W1^T) ----------
    int gid = cyc * 8 + (r - 5);
    if (gid >= gBlocks) return;
    int ty = t >> 4, tx = t & 15;
    int nodeBase = gid * 64;
    const float4* W14 = (const float4*)W1;
    const float4* x4 = (const float4*)(x + (size_t)nodeBase * DIN);
    int limf4 = (n - nodeBase) * (DIN / 4);

    float acc[4][4] = {};
    #pragma unroll
    for (int c = 0; c < 2; ++c) {
        if (c) __syncthreads();
        #pragma unroll
        for (int i = 0; i < 4; ++i) {
            int e = t + i * 256;
            int rr = e >> 4, c4 = e & 15;
            int f4 = rr * 32 + c * 16 + c4;
            ws[rr * 16 + (c4 ^ (rr & 15))] = W14[f4];
            float4 v = make_float4(0.f, 0.f, 0.f, 0.f);
            if (f4 < limf4) v = x4[f4];
            xs[rr * 16 + (c4 ^ (rr & 15))] = v;
        }
        __syncthreads();
        #pragma unroll 8
        for (int k4 = 0; k4 < 16; ++k4) {
            float4 xa[4], wb[4];
            #pragma unroll
            for (int i = 0; i < 4; ++i) {
                int rr = ty + 16 * i;
                xa[i] = xs[rr * 16 + (k4 ^ (rr & 15))];
            }
            #pragma unroll
            for (int j = 0; j < 4; ++j) {
                int rr = tx + 16 * j;
                wb[j] = ws[rr * 16 + (k4 ^ (rr & 15))];
            }
            #pragma unroll
            for (int i = 0; i < 4; ++i)
                #pragma unroll
                for (int j = 0; j < 4; ++j)
                    acc[i][j] += xa[i].x * wb[j].x + xa[i].y * wb[j].y +
                                 xa[i].z * wb[j].z + xa[i].w * wb[j].w;
        }
    }
    #pragma unroll
    for (int i = 0; i < 4; ++i) {
        int node = nodeBase + ty + 16 * i;
        if (node < n) {
            #pragma unroll
            for (int j = 0; j < 4; ++j)
                hs_bf[(size_t)node * HDIM + tx + 16 * j] = f2bf(acc[i][j]);
        }
    }
}

// ---- gather with per-edge dinv: hsum[i] = dinv[i]*hs[i] + sum dinv[s]*hs[s];
//      writes bf16 h (raw, pre-activation, pre-dinv[i]) ----
__global__ __launch_bounds__(256) void k_gather(const int* __restrict__ cursor,
                                                const int* __restrict__ slab,
                                                const unsigned short* __restrict__ hs_bf,
                                                unsigned short* __restrict__ h_bf, int n) {
    int tid = threadIdx.x;
    int lane = tid & 63, wave = tid >> 6;
    int grp = lane >> 3;   // edge slot within octet
    int w8 = lane & 7;     // feature octet: feats 8*w8..8*w8+7
    const int NPW = 8;
    int base = blockIdx.x * (4 * NPW) + wave * NPW;
    for (int nn = 0; nn < NPW; ++nn) {
        int node = base + nn;
        if (node >= n) break;
        int c = cursor[node];
        int cs = (c < SLAB) ? c : SLAB;
        int sv = 0;
        float dnv = 0.f;
        if (lane < cs) {
            sv = slab[(size_t)node * SLAB + lane];
            dnv = rsqrtf((float)cursor[sv] + 1.0f);
        }
        float dni = rsqrtf((float)c + 1.0f);
        uint4 v0 = *(const uint4*)(hs_bf + ((size_t)node << 6) + 8 * w8);
        float sw = (grp == 0) ? dni : 0.f;
        float a0 = sw * lo16f(v0.x), a1 = sw * hi16f(v0.x);
        float a2 = sw * lo16f(v0.y), a3 = sw * hi16f(v0.y);
        float a4 = sw * lo16f(v0.z), a5 = sw * hi16f(v0.z);
        float a6 = sw * lo16f(v0.w), a7 = sw * hi16f(v0.w);
        int nfull = cs >> 3;
        for (int q = 0; q < nfull; ++q) {
            int s = __shfl(sv, 8 * q + grp);
            float dn = __shfl(dnv, 8 * q + grp);
            uint4 v = *(const uint4*)(hs_bf + ((size_t)s << 6) + 8 * w8);
            a0 = fmaf(dn, lo16f(v.x), a0); a1 = fmaf(dn, hi16f(v.x), a1);
            a2 = fmaf(dn, lo16f(v.y), a2); a3 = fmaf(dn, hi16f(v.y), a3);
            a4 = fmaf(dn, lo16f(v.z), a4); a5 = fmaf(dn, hi16f(v.z), a5);
            a6 = fmaf(dn, lo16f(v.w), a6); a7 = fmaf(dn, hi16f(v.w), a7);
        }
        int rm = cs & 7;
        if (rm) {
            int e = 8 * nfull + grp;
            int idx = (e < SLAB) ? e : 0;
            float wt = (grp < rm) ? 1.f : 0.f;
            int s = __shfl(sv, idx);
            float dn = wt * __shfl(dnv, idx);
            uint4 v = *(const uint4*)(hs_bf + ((size_t)s << 6) + 8 * w8);
            a0 = fmaf(dn, lo16f(v.x), a0); a1 = fmaf(dn, hi16f(v.x), a1);
            a2 = fmaf(dn, lo16f(v.y), a2); a3 = fmaf(dn, hi16f(v.y), a3);
            a4 = fmaf(dn, lo16f(v.z), a4); a5 = fmaf(dn, hi16f(v.z), a5);
            a6 = fmaf(dn, lo16f(v.w), a6); a7 = fmaf(dn, hi16f(v.w), a7);
        }
        #define RED(A) A += __shfl_xor(A, 8); A += __shfl_xor(A, 16); A += __shfl_xor(A, 32);
        RED(a0) RED(a1) RED(a2) RED(a3) RED(a4) RED(a5) RED(a6) RED(a7)
        #undef RED
        if (lane < 8) {
            uint4 pk;
            pk.x = (unsigned)f2bf(a0) | ((unsigned)f2bf(a1) << 16);
            pk.y = (unsigned)f2bf(a2) | ((unsigned)f2bf(a3) << 16);
            pk.z = (unsigned)f2bf(a4) | ((unsigned)f2bf(a5) << 16);
            pk.w = (unsigned)f2bf(a6) | ((unsigned)f2bf(a7) << 16);
            *(uint4*)(h_bf + ((size_t)node << 6) + 8 * w8) = pk;
        }
    }
}

// ---- rare overflow (deg > SLAB): single wave, serial, race-free ----
__global__ __launch_bounds__(64) void k_overflow(const int* __restrict__ govf,
                                                 const int* __restrict__ ovf,
                                                 const int* __restrict__ cursor,
                                                 const unsigned short* __restrict__ hs_bf,
                                                 unsigned short* __restrict__ h_bf) {
    int novf = govf[0];
    if (novf > OVF_CAP) novf = OVF_CAP;
    int lane = threadIdx.x;
    for (int i = 0; i < novf; ++i) {
        int d = ovf[2 * i], s = ovf[2 * i + 1];
        float dn = rsqrtf((float)cursor[s] + 1.0f);
        float hv = lo16f((unsigned)h_bf[(size_t)d * HDIM + lane]);
        float av = lo16f((unsigned)hs_bf[(size_t)s * HDIM + lane]);
        h_bf[(size_t)d * HDIM + lane] = f2bf(fmaf(dn, av, hv));
    }
}

// ---- out GEMM: h = relu(dinv*hsum + b1); out = [h@Wmu^T+bmu ; h@Wlv^T+blv] ----
__global__ __launch_bounds__(256) void k_out(const unsigned short* __restrict__ h_bf,
                                             const int* __restrict__ cursor,
                                             const float* __restrict__ b1,
                                             const float* __restrict__ Wmu,
                                             const float* __restrict__ bmu,
                                             const float* __restrict__ Wlv,
                                             const float* __restrict__ blv,
                                             float* __restrict__ out, int n) {
    __shared__ float4 xs[64 * 16];   // activated h tile (16 KB)
    __shared__ uint2 wsb[128 * 16];  // packed-bf16 [Wmu;Wlv] (16 KB)
    int t = threadIdx.x;
    int ty = t >> 4;
    int tx = t & 15;
    int nodeBase = blockIdx.x * 64;

    // stage packed weights
    #pragma unroll
    for (int i = 0; i < 8; ++i) {
        int e = t + i * 256;  // 0..2047
        int r = e >> 4, c4 = e & 15;
        const float4* Wr = (r < 64) ? ((const float4*)Wmu + r * 16)
                                    : ((const float4*)Wlv + (r - 64) * 16);
        float4 wv = Wr[c4];
        uint2 pk;
        pk.x = (unsigned)f2bf(wv.x) | ((unsigned)f2bf(wv.y) << 16);
        pk.y = (unsigned)f2bf(wv.z) | ((unsigned)f2bf(wv.w) << 16);
        wsb[r * 16 + (c4 ^ (r & 15))] = pk;
    }
    // stage h tile (bf16) with fused activation
    int limf4 = (n - nodeBase) * (HDIM / 4);
    #pragma unroll
    for (int i = 0; i < 4; ++i) {
        int f = t + i * 256;
        int r = f >> 4, c4 = f & 15;
        float4 v = make_float4(0.f, 0.f, 0.f, 0.f);
        if (f < limf4) {
            uint2 hv = *(const uint2*)(h_bf + (size_t)nodeBase * HDIM + 4 * (size_t)f);
            float dn = rsqrtf((float)cursor[nodeBase + r] + 1.0f);
            float4 bb = ((const float4*)b1)[c4];
            v.x = fmaxf(fmaf(lo16f(hv.x), dn, bb.x), 0.f);
            v.y = fmaxf(fmaf(hi16f(hv.x), dn, bb.y), 0.f);
            v.z = fmaxf(fmaf(lo16f(hv.y), dn, bb.z), 0.f);
            v.w = fmaxf(fmaf(hi16f(hv.y), dn, bb.w), 0.f);
        }
        xs[r * 16 + (c4 ^ (r & 15))] = v;
    }
    float bias[8];
    #pragma unroll
    for (int j = 0; j < 8; ++j) {
        int o = tx + 16 * j;
        bias[j] = (o < 64) ? bmu[o] : blv[o - 64];
    }
    __syncthreads();

    float acc[4][8] = {};
    #pragma unroll 4
    for (int k4 = 0; k4 < 16; ++k4) {
        float4 xa[4];
        #pragma unroll
        for (int i = 0; i < 4; ++i) {
            int r = ty + 16 * i;
            xa[i] = xs[r * 16 + (k4 ^ (r & 15))];
        }
        #pragma unroll
        for (int j = 0; j < 8; ++j) {
            int r = tx + 16 * j;
            uint2 wv = wsb[r * 16 + (k4 ^ (r & 15))];
            float w0 = lo16f(wv.x), w1 = hi16f(wv.x);
            float w2 = lo16f(wv.y), w3 = hi16f(wv.y);
            #pragma unroll
            for (int i = 0; i < 4; ++i)
                acc[i][j] += xa[i].x * w0 + xa[i].y * w1 + xa[i].z * w2 + xa[i].w * w3;
        }
    }
    #pragma unroll
    for (int i = 0; i < 4; ++i) {
        int node = nodeBase + ty + 16 * i;
        if (node < n) {
            #pragma unroll
            for (int j = 0; j < 8; ++j) {
                int o = tx + 16 * j;
                float val = acc[i][j] + bias[j];
                if (o < 64)
                    out[(size_t)node * HDIM + o] = val;
                else
                    out[(size_t)n * HDIM + (size_t)node * HDIM + (o - 64)] = val;
            }
        }
    }
}

extern "C" void kernel_launch(void* const* d_in, const int* in_sizes, int n_in,
                              void* d_out, int out_size, void* d_ws, size_t ws_size,
                              hipStream_t stream) {
    const float* x   = (const float*)d_in[0];
    const int*   ei  = (const int*)d_in[1];
    const float* W1  = (const float*)d_in[2];
    const float* b1  = (const float*)d_in[3];
    const float* Wmu = (const float*)d_in[4];
    const float* bmu = (const float*)d_in[5];
    const float* Wlv = (const float*)d_in[6];
    const float* blv = (const float*)d_in[7];
    float* out = (float*)d_out;

    const int N = in_sizes[0] / DIN;   // 100000
    const int E = in_sizes[1] / 2;     // 1000000
    const int* src = ei;
    const int* dst = ei + E;

    auto align256 = [](size_t b) { return (b + 255) & ~(size_t)255; };
    char* ws = (char*)d_ws;
    size_t off = 0;
    int* cursor = (int*)(ws + off); off += align256((size_t)N * 4);
    int* govf   = (int*)(ws + off); off += 256;
    int* slab   = (int*)(ws + off); off += align256((size_t)N * SLAB * 4);
    int* ovf    = (int*)(ws + off); off += align256((size_t)OVF_CAP * 2 * 4);
    unsigned short* hs_bf = (unsigned short*)(ws + off);
    off += align256((size_t)N * HDIM * 2);
    unsigned short* h_bf = (unsigned short*)(ws + off);
    off += align256((size_t)N * HDIM * 2);

    hipMemsetAsync(cursor, 0, align256((size_t)N * 4) + 256, stream);

    int scBlocks = (E + 1023) / 1024;      // 977
    int gBlocks  = (N + 63) / 64;          // 1563
    int cycles = max((scBlocks + 4) / 5, (gBlocks + 7) / 8);  // 196
    k_front<<<cycles * 13, 256, 0, stream>>>(src, dst, cursor, slab, ovf, govf,
                                             E, scBlocks, x, W1, hs_bf, N, gBlocks);
    k_gather<<<(N + 31) / 32, 256, 0, stream>>>(cursor, slab, hs_bf, h_bf, N);
    k_overflow<<<1, 64, 0, stream>>>(govf, ovf, cursor, hs_bf, h_bf);
    k_out<<<(N + 63) / 64, 256, 0, stream>>>(h_bf, cursor, b1, Wmu, bmu, Wlv, blv,
                                             out, N);
}